// Round 3
// baseline (87.122 us; speedup 1.0000x reference)
//
#include <hip/hip_runtime.h>
#include <math.h>

// FFT circular conv: y[b,h,:] = irfft(rfft(x[b,h,:]) * rfft(k[h,:])), N=4096.
// M=2048 complex FFT via even/odd packing. Stockham radix 8,8,8,4, in-place
// LDS (float2 interleaved, b64 access), global twiddle tables, pointwise
// multiply fused into the forward final radix-4 stage via butterfly pairing.

#define NT 256
#define KF_LD 2049
#define C_SQRT1_2 0.70710678118654752f

// Element-index swizzle for float2 LDS: spreads stride-16/128/256/512
// patterns to exactly 2 lanes per 8B slot. Involution (mask bits 4-7 -> 0-3).
__device__ __forceinline__ int SWE(int e) { return e ^ ((e >> 4) & 15); }

template <int SIGN>
__device__ __forceinline__ void bf8(const float2 a[8], float2 b[8]) {
  float s0r = a[0].x + a[4].x, s0i = a[0].y + a[4].y;
  float s1r = a[0].x - a[4].x, s1i = a[0].y - a[4].y;
  float s2r = a[2].x + a[6].x, s2i = a[2].y + a[6].y;
  float s3r = a[2].x - a[6].x, s3i = a[2].y - a[6].y;
  float E0r = s0r + s2r, E0i = s0i + s2i;
  float E2r = s0r - s2r, E2i = s0i - s2i;
  float E1r, E1i, E3r, E3i;
  if (SIGN < 0) { E1r = s1r + s3i; E1i = s1i - s3r; E3r = s1r - s3i; E3i = s1i + s3r; }
  else          { E1r = s1r - s3i; E1i = s1i + s3r; E3r = s1r + s3i; E3i = s1i - s3r; }
  float u0r = a[1].x + a[5].x, u0i = a[1].y + a[5].y;
  float u1r = a[1].x - a[5].x, u1i = a[1].y - a[5].y;
  float u2r = a[3].x + a[7].x, u2i = a[3].y + a[7].y;
  float u3r = a[3].x - a[7].x, u3i = a[3].y - a[7].y;
  float O0r = u0r + u2r, O0i = u0i + u2i;
  float O2r = u0r - u2r, O2i = u0i - u2i;
  float O1r, O1i, O3r, O3i;
  if (SIGN < 0) { O1r = u1r + u3i; O1i = u1i - u3r; O3r = u1r - u3i; O3i = u1i + u3r; }
  else          { O1r = u1r - u3i; O1i = u1i + u3r; O3r = u1r + u3i; O3i = u1i - u3r; }
  float t1r, t1i, t2r, t2i, t3r, t3i;
  if (SIGN < 0) {
    t1r = C_SQRT1_2 * (O1r + O1i); t1i = C_SQRT1_2 * (O1i - O1r);
    t2r = O2i;  t2i = -O2r;
    t3r = C_SQRT1_2 * (O3i - O3r); t3i = -C_SQRT1_2 * (O3r + O3i);
  } else {
    t1r = C_SQRT1_2 * (O1r - O1i); t1i = C_SQRT1_2 * (O1i + O1r);
    t2r = -O2i; t2i = O2r;
    t3r = -C_SQRT1_2 * (O3r + O3i); t3i = C_SQRT1_2 * (O3r - O3i);
  }
  b[0] = make_float2(E0r + O0r, E0i + O0i);
  b[4] = make_float2(E0r - O0r, E0i - O0i);
  b[1] = make_float2(E1r + t1r, E1i + t1i);
  b[5] = make_float2(E1r - t1r, E1i - t1i);
  b[2] = make_float2(E2r + t2r, E2i + t2i);
  b[6] = make_float2(E2r - t2r, E2i - t2i);
  b[3] = make_float2(E3r + t3r, E3i + t3i);
  b[7] = make_float2(E3r - t3r, E3i - t3i);
}

// In-place Stockham radix-8 stage with table twiddles (tw[j] = e^{+2pi i j/2048}).
template <int SIGN, int S>
__device__ __forceinline__ void stage_r8_ip(float2* Z, const float2* __restrict__ tw,
                                            const int rd[8]) {
  const int t = (int)threadIdx.x;
  const int q = t & (S - 1);
  const int p = t / S;
  float2 a[8];
#pragma unroll
  for (int j = 0; j < 8; ++j) a[j] = Z[rd[j]];
  float2 b[8];
  bf8<SIGN>(a, b);
  float2 w[7];
#pragma unroll
  for (int m = 1; m < 8; ++m) w[m - 1] = tw[S * p * m];
  __syncthreads();
  const int ob = q + 8 * S * p;
  Z[SWE(ob)] = b[0];
#pragma unroll
  for (int m = 1; m < 8; ++m) {
    const float wr = w[m - 1].x;
    const float wi = (SIGN > 0) ? w[m - 1].y : -w[m - 1].y;
    Z[SWE(ob + S * m)] = make_float2(b[m].x * wr - b[m].y * wi,
                                     b[m].x * wi + b[m].y * wr);
  }
  __syncthreads();
}

// Stage 1 (S=1) fused with the global load (src = packed complex row).
template <int SIGN>
__device__ __forceinline__ void stage1_global(const float2* __restrict__ src,
                                              float2* Z, const float2* __restrict__ tw) {
  const int t = (int)threadIdx.x;
  float2 a[8];
#pragma unroll
  for (int j = 0; j < 8; ++j) a[j] = src[t + 256 * j];
  float2 b[8];
  bf8<SIGN>(a, b);
  float2 w[7];
#pragma unroll
  for (int m = 1; m < 8; ++m) w[m - 1] = tw[t * m];
  const int ob = 8 * t;
  Z[SWE(ob)] = b[0];
#pragma unroll
  for (int m = 1; m < 8; ++m) {
    const float wr = w[m - 1].x;
    const float wi = (SIGN > 0) ? w[m - 1].y : -w[m - 1].y;
    Z[SWE(ob + m)] = make_float2(b[m].x * wr - b[m].y * wi,
                                 b[m].x * wi + b[m].y * wr);
  }
  __syncthreads();
}

// Forward radix-4 final-stage butterfly (twiddle-free), reads LDS.
__device__ __forceinline__ void bf4f(const float2* Z, int b, float2 o[4]) {
  float2 a0 = Z[SWE(b)], a1 = Z[SWE(b + 512)];
  float2 a2 = Z[SWE(b + 1024)], a3 = Z[SWE(b + 1536)];
  float s0r = a0.x + a2.x, s0i = a0.y + a2.y;
  float s1r = a0.x - a2.x, s1i = a0.y - a2.y;
  float s2r = a1.x + a3.x, s2i = a1.y + a3.y;
  float s3r = a1.x - a3.x, s3i = a1.y - a3.y;
  o[0] = make_float2(s0r + s2r, s0i + s2i);
  o[1] = make_float2(s1r + s3i, s1i - s3r);
  o[2] = make_float2(s0r - s2r, s0i - s2i);
  o[3] = make_float2(s1r - s3i, s1i + s3r);
}

// rfft-unpack of conjugate pair (klo, 2048-klo), pointwise multiply by kf,
// repack to Z2 values for the inverse complex FFT.
__device__ __forceinline__ void pw_pair(int klo, float2 P, float2 Q,
                                        const float2* __restrict__ kfrow,
                                        const float2* __restrict__ utw,
                                        float2& zlo, float2& zhi) {
  const float Er = 0.5f * (P.x + Q.x), Ei = 0.5f * (P.y - Q.y);
  const float Or = 0.5f * (P.y + Q.y), Oi = 0.5f * (Q.x - P.x);
  const float2 w = utw[klo];
  const float cs = w.x, sn = w.y;
  const float Xpr = Er + cs * Or + sn * Oi, Xpi = Ei + cs * Oi - sn * Or;
  const float Xqr = Er - cs * Or - sn * Oi, Xqi = -Ei + cs * Oi - sn * Or;
  const float2 Kp = kfrow[klo];
  const float2 Kq = kfrow[2048 - klo];
  const float Ypr = Xpr * Kp.x - Xpi * Kp.y, Ypi = Xpr * Kp.y + Xpi * Kp.x;
  const float Yqr = Xqr * Kq.x - Xqi * Kq.y, Yqi = Xqr * Kq.y + Xqi * Kq.x;
  const float Epr = 0.5f * (Ypr + Yqr), Epi = 0.5f * (Ypi - Yqi);
  const float Dr = 0.5f * (Ypr - Yqr), Di = 0.5f * (Ypi + Yqi);
  zlo = make_float2(Epr - cs * Di - sn * Dr, Epi + cs * Dr - sn * Di);
  zhi = make_float2(Epr + cs * Di + sn * Dr, -Epi + cs * Dr - sn * Di);
}

// Forward final radix-4 stage fused with unpack * kf * repack. Thread t does
// butterflies t and 512-t (t=0: 0 and 256): their 8 outputs form exactly the
// conjugate pairs (kk, 2048-kk). In-place safe (writes == reads set).
__device__ __forceinline__ void fwd4_pw(float2* Z, const float2* __restrict__ kfrow,
                                        const float2* __restrict__ utw) {
  const int t = (int)threadIdx.x;
  const int b1 = (t == 0) ? 256 : 512 - t;
  float2 A[4], B[4];
  bf4f(Z, t, A);
  bf4f(Z, b1, B);
  int k0, k1, k2, k3;
  float2 zl0, zh0, zl1, zh1, zl2, zh2, zl3, zh3, zl4;
  zl4 = make_float2(0.f, 0.f);
  if (t == 0) {
    float2 zh4;
    k0 = 0;   pw_pair(0, A[0], A[0], kfrow, utw, zl0, zh0);
    k1 = 512; pw_pair(512, A[1], A[3], kfrow, utw, zl1, zh1);
    k2 = 256; pw_pair(256, B[0], B[3], kfrow, utw, zl2, zh2);
    k3 = 768; pw_pair(768, B[1], B[2], kfrow, utw, zl3, zh3);
    pw_pair(1024, A[2], A[2], kfrow, utw, zl4, zh4);
  } else {
    k0 = t;        pw_pair(k0, A[0], B[3], kfrow, utw, zl0, zh0);
    k1 = t + 512;  pw_pair(k1, A[1], B[2], kfrow, utw, zl1, zh1);
    k2 = 1024 - t; pw_pair(k2, B[1], A[2], kfrow, utw, zl2, zh2);
    k3 = 512 - t;  pw_pair(k3, B[0], A[3], kfrow, utw, zl3, zh3);
  }
  __syncthreads();
  Z[SWE(k0)] = zl0; Z[SWE((2048 - k0) & 2047)] = zh0;
  Z[SWE(k1)] = zl1; Z[SWE(2048 - k1)] = zh1;
  Z[SWE(k2)] = zl2; Z[SWE(2048 - k2)] = zh2;
  Z[SWE(k3)] = zl3; Z[SWE(2048 - k3)] = zh3;
  if (t == 0) Z[SWE(1024)] = zl4;
  __syncthreads();
}

// Inverse final radix-4 stage (twiddle-free) fused with the global store.
__device__ __forceinline__ void inv4_store(const float2* Z, float2* __restrict__ dst) {
  const int t = (int)threadIdx.x;
#pragma unroll
  for (int c = 0; c < 2; ++c) {
    const int b = t + 256 * c;
    float2 a0 = Z[SWE(b)], a1 = Z[SWE(b + 512)];
    float2 a2 = Z[SWE(b + 1024)], a3 = Z[SWE(b + 1536)];
    float s0r = a0.x + a2.x, s0i = a0.y + a2.y;
    float s1r = a0.x - a2.x, s1i = a0.y - a2.y;
    float s2r = a1.x + a3.x, s2i = a1.y + a3.y;
    float s3r = a1.x - a3.x, s3i = a1.y - a3.y;
    dst[b]        = make_float2(s0r + s2r, s0i + s2i);
    dst[b + 512]  = make_float2(s1r - s3i, s1i + s3r);
    dst[b + 1024] = make_float2(s0r - s2r, s0i - s2i);
    dst[b + 1536] = make_float2(s1r + s3i, s1i - s3r);
  }
}

// Forward radix-4 final stage, plain (kfft): writes spectrum back to LDS.
__device__ __forceinline__ void stage_r4_ip_fwd(float2* Z) {
  const int t = (int)threadIdx.x;
  float2 O0[4], O1[4];
  bf4f(Z, t, O0);
  bf4f(Z, t + 256, O1);
  __syncthreads();
#pragma unroll
  for (int m = 0; m < 4; ++m) {
    Z[SWE(t + 512 * m)] = O0[m];
    Z[SWE(t + 256 + 512 * m)] = O1[m];
  }
  __syncthreads();
}

__device__ __forceinline__ void unpackX(float2 P, float2 Q, float2 w,
                                        float2& Xp, float2& Xq) {
  const float Er = 0.5f * (P.x + Q.x), Ei = 0.5f * (P.y - Q.y);
  const float Or = 0.5f * (P.y + Q.y), Oi = 0.5f * (Q.x - P.x);
  const float cs = w.x, sn = w.y;
  Xp = make_float2(Er + cs * Or + sn * Oi, Ei + cs * Oi - sn * Or);
  Xq = make_float2(Er - cs * Or - sn * Oi, -Ei + cs * Oi - sn * Or);
}

__global__ void init_tables(float2* __restrict__ tw, float2* __restrict__ utw) {
  const int g = (int)(blockIdx.x * blockDim.x + threadIdx.x);
  if (g < 2048) {
    const double a = 6.283185307179586476925286766559 * (double)g / 2048.0;
    tw[g] = make_float2((float)cos(a), (float)sin(a));
  } else if (g < 2048 + 1025) {
    const int j = g - 2048;
    const double a = 6.283185307179586476925286766559 * (double)j / 4096.0;
    utw[j] = make_float2((float)cos(a), (float)sin(a));
  }
}

__global__ __launch_bounds__(NT) void kfft_kernel(const float* __restrict__ kin,
                                                  float2* __restrict__ kf,
                                                  const float2* __restrict__ tw,
                                                  const float2* __restrict__ utw) {
  __shared__ float2 Z[2048];
  const int t = (int)threadIdx.x;
  const int h = (int)blockIdx.x;
  const float2* src = (const float2*)(kin + (size_t)h * 4096);
  int rd[8];
#pragma unroll
  for (int j = 0; j < 8; ++j) rd[j] = SWE(t + 256 * j);
  stage1_global<-1>(src, Z, tw);
  stage_r8_ip<-1, 8>(Z, tw, rd);
  stage_r8_ip<-1, 64>(Z, tw, rd);
  stage_r4_ip_fwd(Z);
  const float sc = 1.0f / 2048.0f;  // folded inverse-FFT normalization
  float2* kfrow = kf + (size_t)h * KF_LD;
#pragma unroll
  for (int u = 0; u < 4; ++u) {
    const int kk = t + 256 * u;  // 0..1023
    const float2 P = Z[SWE(kk)];
    const float2 Q = Z[SWE((2048 - kk) & 2047)];
    float2 Xp, Xq;
    unpackX(P, Q, utw[kk], Xp, Xq);
    kfrow[kk] = make_float2(Xp.x * sc, Xp.y * sc);
    kfrow[2048 - kk] = make_float2(Xq.x * sc, Xq.y * sc);
  }
  if (t == 0) {
    const float2 P = Z[SWE(1024)];
    float2 Xp, Xq;
    unpackX(P, P, utw[1024], Xp, Xq);
    kfrow[1024] = make_float2(Xp.x * sc, Xp.y * sc);
  }
}

__global__ __launch_bounds__(NT) void conv_kernel(const float* __restrict__ x,
                                                  const float2* __restrict__ kf,
                                                  const float2* __restrict__ tw,
                                                  const float2* __restrict__ utw,
                                                  float* __restrict__ y, int H) {
  __shared__ float2 Z[2048];
  const int t = (int)threadIdx.x;
  const int bi = (int)blockIdx.x;
  const int b = bi & 7;   // batch (8 consecutive blocks share one kf row)
  const int h = bi >> 3;
  const int row = b * H + h;
  const float2* src = (const float2*)(x + (size_t)row * 4096);
  float2* dst = (float2*)(y + (size_t)row * 4096);
  const float2* kfrow = kf + (size_t)h * KF_LD;
  int rd[8];
#pragma unroll
  for (int j = 0; j < 8; ++j) rd[j] = SWE(t + 256 * j);
  stage1_global<-1>(src, Z, tw);       // fwd S=1 (r8), fused global load
  stage_r8_ip<-1, 8>(Z, tw, rd);       // fwd S=8
  stage_r8_ip<-1, 64>(Z, tw, rd);      // fwd S=64
  fwd4_pw(Z, kfrow, utw);              // fwd S=512 (r4) + pointwise, fused
  stage_r8_ip<1, 1>(Z, tw, rd);        // inv S=1
  stage_r8_ip<1, 8>(Z, tw, rd);        // inv S=8
  stage_r8_ip<1, 64>(Z, tw, rd);       // inv S=64
  inv4_store(Z, dst);                  // inv S=512 (r4), fused global store
}

extern "C" void kernel_launch(void* const* d_in, const int* in_sizes, int n_in,
                              void* d_out, int out_size, void* d_ws, size_t ws_size,
                              hipStream_t stream) {
  const float* x = (const float*)d_in[0];
  const float* kin = (const float*)d_in[1];
  float* y = (float*)d_out;
  const int H = in_sizes[1] / 4096;    // 768
  const int BH = in_sizes[0] / 4096;   // 6144
  float2* kf = (float2*)d_ws;          // 768*2049*8B = 12.59 MB
  float2* tw = kf + (size_t)H * KF_LD; // 16 KB
  float2* utw = tw + 2048;             // 8.2 KB
  hipLaunchKernelGGL(init_tables, dim3(13), dim3(NT), 0, stream, tw, utw);
  hipLaunchKernelGGL(kfft_kernel, dim3(H), dim3(NT), 0, stream, kin, kf, tw, utw);
  hipLaunchKernelGGL(conv_kernel, dim3(BH), dim3(NT), 0, stream, x, kf, tw, utw, y, H);
}

// Round 5
// 85.634 us; speedup vs baseline: 1.0174x; 1.0174x over previous
//
#include <hip/hip_runtime.h>
#include <math.h>

// FFT circular conv: y[b,h,:] = irfft(rfft(x[b,h,:]) * rfft(k[h,:])), N=4096.
// M=2048 complex FFT via even/odd packing. Stockham radix 8,8,8,4 with
// ping-pong LDS (ONE barrier per stage), float2 interleaved (b64 access),
// global twiddle tables, pointwise multiply fused into fwd final stage,
// global load/store fused into first/last stages.

#define NT 256
#define KF_LD 2049
#define C_SQRT1_2 0.70710678118654752f

typedef float f2v __attribute__((ext_vector_type(2)));  // native vec for NT store

__device__ __forceinline__ void nt_store2(float2 v, float2* p) {
  f2v w; w.x = v.x; w.y = v.y;
  __builtin_nontemporal_store(w, (f2v*)p);
}

// Element-index swizzle for float2 LDS: spreads stride-16/128/256/512
// patterns to ~2 lanes per 8B slot. Involution (bits 4-7 XOR into 0-3).
__device__ __forceinline__ int SWE(int e) { return e ^ ((e >> 4) & 15); }

template <int SIGN>
__device__ __forceinline__ void bf8(const float2 a[8], float2 b[8]) {
  float s0r = a[0].x + a[4].x, s0i = a[0].y + a[4].y;
  float s1r = a[0].x - a[4].x, s1i = a[0].y - a[4].y;
  float s2r = a[2].x + a[6].x, s2i = a[2].y + a[6].y;
  float s3r = a[2].x - a[6].x, s3i = a[2].y - a[6].y;
  float E0r = s0r + s2r, E0i = s0i + s2i;
  float E2r = s0r - s2r, E2i = s0i - s2i;
  float E1r, E1i, E3r, E3i;
  if (SIGN < 0) { E1r = s1r + s3i; E1i = s1i - s3r; E3r = s1r - s3i; E3i = s1i + s3r; }
  else          { E1r = s1r - s3i; E1i = s1i + s3r; E3r = s1r + s3i; E3i = s1i - s3r; }
  float u0r = a[1].x + a[5].x, u0i = a[1].y + a[5].y;
  float u1r = a[1].x - a[5].x, u1i = a[1].y - a[5].y;
  float u2r = a[3].x + a[7].x, u2i = a[3].y + a[7].y;
  float u3r = a[3].x - a[7].x, u3i = a[3].y - a[7].y;
  float O0r = u0r + u2r, O0i = u0i + u2i;
  float O2r = u0r - u2r, O2i = u0i - u2i;
  float O1r, O1i, O3r, O3i;
  if (SIGN < 0) { O1r = u1r + u3i; O1i = u1i - u3r; O3r = u1r - u3i; O3i = u1i + u3r; }
  else          { O1r = u1r - u3i; O1i = u1i + u3r; O3r = u1r + u3i; O3i = u1i - u3r; }
  float t1r, t1i, t2r, t2i, t3r, t3i;
  if (SIGN < 0) {
    t1r = C_SQRT1_2 * (O1r + O1i); t1i = C_SQRT1_2 * (O1i - O1r);
    t2r = O2i;  t2i = -O2r;
    t3r = C_SQRT1_2 * (O3i - O3r); t3i = -C_SQRT1_2 * (O3r + O3i);
  } else {
    t1r = C_SQRT1_2 * (O1r - O1i); t1i = C_SQRT1_2 * (O1i + O1r);
    t2r = -O2i; t2i = O2r;
    t3r = -C_SQRT1_2 * (O3r + O3i); t3i = C_SQRT1_2 * (O3r - O3i);
  }
  b[0] = make_float2(E0r + O0r, E0i + O0i);
  b[4] = make_float2(E0r - O0r, E0i - O0i);
  b[1] = make_float2(E1r + t1r, E1i + t1i);
  b[5] = make_float2(E1r - t1r, E1i - t1i);
  b[2] = make_float2(E2r + t2r, E2i + t2i);
  b[6] = make_float2(E2r - t2r, E2i - t2i);
  b[3] = make_float2(E3r + t3r, E3i + t3i);
  b[7] = make_float2(E3r - t3r, E3i - t3i);
}

// Out-of-place Stockham radix-8 stage: read X[t+256j], write Y (twiddled).
// No internal barrier — caller syncs after.
template <int SIGN, int S>
__device__ __forceinline__ void stage_r8(const float2* X, float2* Y,
                                         const float2* __restrict__ tw,
                                         const int rd[8]) {
  const int t = (int)threadIdx.x;
  const int q = t & (S - 1);
  const int p = t / S;
  float2 a[8];
#pragma unroll
  for (int j = 0; j < 8; ++j) a[j] = X[rd[j]];
  float2 b[8];
  bf8<SIGN>(a, b);
  const int ob = q + 8 * S * p;
  Y[SWE(ob)] = b[0];
#pragma unroll
  for (int m = 1; m < 8; ++m) {
    const float2 w = tw[S * p * m];
    const float wr = w.x;
    const float wi = (SIGN > 0) ? w.y : -w.y;
    Y[SWE(ob + S * m)] = make_float2(b[m].x * wr - b[m].y * wi,
                                     b[m].x * wi + b[m].y * wr);
  }
}

// Stage 1 (S=1) fused with the global load (src = packed complex row).
template <int SIGN>
__device__ __forceinline__ void stage1_global(const float2* __restrict__ src,
                                              float2* Y, const float2* __restrict__ tw) {
  const int t = (int)threadIdx.x;
  float2 a[8];
#pragma unroll
  for (int j = 0; j < 8; ++j) a[j] = src[t + 256 * j];
  float2 b[8];
  bf8<SIGN>(a, b);
  const int ob = 8 * t;
  Y[SWE(ob)] = b[0];
#pragma unroll
  for (int m = 1; m < 8; ++m) {
    const float2 w = tw[t * m];
    const float wr = w.x;
    const float wi = (SIGN > 0) ? w.y : -w.y;
    Y[SWE(ob + m)] = make_float2(b[m].x * wr - b[m].y * wi,
                                 b[m].x * wi + b[m].y * wr);
  }
}

// Forward radix-4 final-stage butterfly (twiddle-free), reads X.
__device__ __forceinline__ void bf4f(const float2* X, int b, float2 o[4]) {
  float2 a0 = X[SWE(b)], a1 = X[SWE(b + 512)];
  float2 a2 = X[SWE(b + 1024)], a3 = X[SWE(b + 1536)];
  float s0r = a0.x + a2.x, s0i = a0.y + a2.y;
  float s1r = a0.x - a2.x, s1i = a0.y - a2.y;
  float s2r = a1.x + a3.x, s2i = a1.y + a3.y;
  float s3r = a1.x - a3.x, s3i = a1.y - a3.y;
  o[0] = make_float2(s0r + s2r, s0i + s2i);
  o[1] = make_float2(s1r + s3i, s1i - s3r);
  o[2] = make_float2(s0r - s2r, s0i - s2i);
  o[3] = make_float2(s1r - s3i, s1i + s3r);
}

// rfft-unpack of conjugate pair (klo, 2048-klo), pointwise multiply by kf,
// repack to Z2 values for the inverse complex FFT.
__device__ __forceinline__ void pw_pair(int klo, float2 P, float2 Q,
                                        const float2* __restrict__ kfrow,
                                        const float2* __restrict__ utw,
                                        float2& zlo, float2& zhi) {
  const float Er = 0.5f * (P.x + Q.x), Ei = 0.5f * (P.y - Q.y);
  const float Or = 0.5f * (P.y + Q.y), Oi = 0.5f * (Q.x - P.x);
  const float2 w = utw[klo];
  const float cs = w.x, sn = w.y;
  const float Xpr = Er + cs * Or + sn * Oi, Xpi = Ei + cs * Oi - sn * Or;
  const float Xqr = Er - cs * Or - sn * Oi, Xqi = -Ei + cs * Oi - sn * Or;
  const float2 Kp = kfrow[klo];
  const float2 Kq = kfrow[2048 - klo];
  const float Ypr = Xpr * Kp.x - Xpi * Kp.y, Ypi = Xpr * Kp.y + Xpi * Kp.x;
  const float Yqr = Xqr * Kq.x - Xqi * Kq.y, Yqi = Xqr * Kq.y + Xqi * Kq.x;
  const float Epr = 0.5f * (Ypr + Yqr), Epi = 0.5f * (Ypi - Yqi);
  const float Dr = 0.5f * (Ypr - Yqr), Di = 0.5f * (Ypi + Yqi);
  zlo = make_float2(Epr - cs * Di - sn * Dr, Epi + cs * Dr - sn * Di);
  zhi = make_float2(Epr + cs * Di + sn * Dr, -Epi + cs * Dr - sn * Di);
}

// Forward final radix-4 stage fused with unpack * kf * repack, out-of-place
// (read X, write Y). Thread t does butterflies t and 512-t (t=0: 0 and 256):
// their 8 outputs form exactly the conjugate pairs (kk, 2048-kk).
__device__ __forceinline__ void fwd4_pw(const float2* X, float2* Y,
                                        const float2* __restrict__ kfrow,
                                        const float2* __restrict__ utw) {
  const int t = (int)threadIdx.x;
  const int b1 = (t == 0) ? 256 : 512 - t;
  float2 A[4], B[4];
  bf4f(X, t, A);
  bf4f(X, b1, B);
  int k0, k1, k2, k3;
  float2 zl0, zh0, zl1, zh1, zl2, zh2, zl3, zh3, zl4;
  zl4 = make_float2(0.f, 0.f);
  if (t == 0) {
    float2 zh4;
    k0 = 0;   pw_pair(0, A[0], A[0], kfrow, utw, zl0, zh0);
    k1 = 512; pw_pair(512, A[1], A[3], kfrow, utw, zl1, zh1);
    k2 = 256; pw_pair(256, B[0], B[3], kfrow, utw, zl2, zh2);
    k3 = 768; pw_pair(768, B[1], B[2], kfrow, utw, zl3, zh3);
    pw_pair(1024, A[2], A[2], kfrow, utw, zl4, zh4);
  } else {
    k0 = t;        pw_pair(k0, A[0], B[3], kfrow, utw, zl0, zh0);
    k1 = t + 512;  pw_pair(k1, A[1], B[2], kfrow, utw, zl1, zh1);
    k2 = 1024 - t; pw_pair(k2, B[1], A[2], kfrow, utw, zl2, zh2);
    k3 = 512 - t;  pw_pair(k3, B[0], A[3], kfrow, utw, zl3, zh3);
  }
  Y[SWE(k0)] = zl0; Y[SWE((2048 - k0) & 2047)] = zh0;
  Y[SWE(k1)] = zl1; Y[SWE(2048 - k1)] = zh1;
  Y[SWE(k2)] = zl2; Y[SWE(2048 - k2)] = zh2;
  Y[SWE(k3)] = zl3; Y[SWE(2048 - k3)] = zh3;
  if (t == 0) Y[SWE(1024)] = zl4;
}

// Inverse final radix-4 stage (twiddle-free) fused with the global store.
__device__ __forceinline__ void inv4_store(const float2* X, float2* __restrict__ dst) {
  const int t = (int)threadIdx.x;
#pragma unroll
  for (int c = 0; c < 2; ++c) {
    const int b = t + 256 * c;
    float2 a0 = X[SWE(b)], a1 = X[SWE(b + 512)];
    float2 a2 = X[SWE(b + 1024)], a3 = X[SWE(b + 1536)];
    float s0r = a0.x + a2.x, s0i = a0.y + a2.y;
    float s1r = a0.x - a2.x, s1i = a0.y - a2.y;
    float s2r = a1.x + a3.x, s2i = a1.y + a3.y;
    float s3r = a1.x - a3.x, s3i = a1.y - a3.y;
    nt_store2(make_float2(s0r + s2r, s0i + s2i), &dst[b]);
    nt_store2(make_float2(s1r - s3i, s1i + s3r), &dst[b + 512]);
    nt_store2(make_float2(s0r - s2r, s0i - s2i), &dst[b + 1024]);
    nt_store2(make_float2(s1r + s3i, s1i - s3r), &dst[b + 1536]);
  }
}

// Forward radix-4 final stage, plain, out-of-place (kfft path).
__device__ __forceinline__ void stage_r4_fwd(const float2* X, float2* Y) {
  const int t = (int)threadIdx.x;
  float2 O0[4], O1[4];
  bf4f(X, t, O0);
  bf4f(X, t + 256, O1);
#pragma unroll
  for (int m = 0; m < 4; ++m) {
    Y[SWE(t + 512 * m)] = O0[m];
    Y[SWE(t + 256 + 512 * m)] = O1[m];
  }
}

__device__ __forceinline__ void unpackX(float2 P, float2 Q, float2 w,
                                        float2& Xp, float2& Xq) {
  const float Er = 0.5f * (P.x + Q.x), Ei = 0.5f * (P.y - Q.y);
  const float Or = 0.5f * (P.y + Q.y), Oi = 0.5f * (Q.x - P.x);
  const float cs = w.x, sn = w.y;
  Xp = make_float2(Er + cs * Or + sn * Oi, Ei + cs * Oi - sn * Or);
  Xq = make_float2(Er - cs * Or - sn * Oi, -Ei + cs * Oi - sn * Or);
}

__global__ void init_tables(float2* __restrict__ tw, float2* __restrict__ utw) {
  const int g = (int)(blockIdx.x * blockDim.x + threadIdx.x);
  if (g < 2048) {
    const double a = 6.283185307179586476925286766559 * (double)g / 2048.0;
    tw[g] = make_float2((float)cos(a), (float)sin(a));
  } else if (g < 2048 + 1025) {
    const int j = g - 2048;
    const double a = 6.283185307179586476925286766559 * (double)j / 4096.0;
    utw[j] = make_float2((float)cos(a), (float)sin(a));
  }
}

__global__ __launch_bounds__(NT) void kfft_kernel(const float* __restrict__ kin,
                                                  float2* __restrict__ kf,
                                                  const float2* __restrict__ tw,
                                                  const float2* __restrict__ utw) {
  __shared__ float2 ZA[2048];
  __shared__ float2 ZB[2048];
  const int t = (int)threadIdx.x;
  const int h = (int)blockIdx.x;
  const float2* src = (const float2*)(kin + (size_t)h * 4096);
  int rd[8];
#pragma unroll
  for (int j = 0; j < 8; ++j) rd[j] = SWE(t + 256 * j);
  stage1_global<-1>(src, ZA, tw);
  __syncthreads();
  stage_r8<-1, 8>(ZA, ZB, tw, rd);
  __syncthreads();
  stage_r8<-1, 64>(ZB, ZA, tw, rd);
  __syncthreads();
  stage_r4_fwd(ZA, ZB);
  __syncthreads();
  const float sc = 1.0f / 2048.0f;  // folded inverse-FFT normalization
  float2* kfrow = kf + (size_t)h * KF_LD;
#pragma unroll
  for (int u = 0; u < 4; ++u) {
    const int kk = t + 256 * u;  // 0..1023
    const float2 P = ZB[SWE(kk)];
    const float2 Q = ZB[SWE((2048 - kk) & 2047)];
    float2 Xp, Xq;
    unpackX(P, Q, utw[kk], Xp, Xq);
    kfrow[kk] = make_float2(Xp.x * sc, Xp.y * sc);
    kfrow[2048 - kk] = make_float2(Xq.x * sc, Xq.y * sc);
  }
  if (t == 0) {
    const float2 P = ZB[SWE(1024)];
    float2 Xp, Xq;
    unpackX(P, P, utw[1024], Xp, Xq);
    kfrow[1024] = make_float2(Xp.x * sc, Xp.y * sc);
  }
}

__global__ __launch_bounds__(NT) void conv_kernel(const float* __restrict__ x,
                                                  const float2* __restrict__ kf,
                                                  const float2* __restrict__ tw,
                                                  const float2* __restrict__ utw,
                                                  float* __restrict__ y, int H) {
  __shared__ float2 ZA[2048];
  __shared__ float2 ZB[2048];
  const int t = (int)threadIdx.x;
  const int bi = (int)blockIdx.x;
  const int b = bi & 7;   // batch (8 consecutive blocks share one kf row)
  const int h = bi >> 3;
  const int row = b * H + h;
  const float2* src = (const float2*)(x + (size_t)row * 4096);
  float2* dst = (float2*)(y + (size_t)row * 4096);
  const float2* kfrow = kf + (size_t)h * KF_LD;
  int rd[8];
#pragma unroll
  for (int j = 0; j < 8; ++j) rd[j] = SWE(t + 256 * j);
  stage1_global<-1>(src, ZA, tw);   // fwd S=1 (r8), fused global load
  __syncthreads();
  stage_r8<-1, 8>(ZA, ZB, tw, rd);  // fwd S=8
  __syncthreads();
  stage_r8<-1, 64>(ZB, ZA, tw, rd); // fwd S=64
  __syncthreads();
  fwd4_pw(ZA, ZB, kfrow, utw);      // fwd S=512 (r4) + pointwise, fused
  __syncthreads();
  stage_r8<1, 1>(ZB, ZA, tw, rd);   // inv S=1
  __syncthreads();
  stage_r8<1, 8>(ZA, ZB, tw, rd);   // inv S=8
  __syncthreads();
  stage_r8<1, 64>(ZB, ZA, tw, rd);  // inv S=64
  __syncthreads();
  inv4_store(ZA, dst);              // inv S=512 (r4), fused global store
}

extern "C" void kernel_launch(void* const* d_in, const int* in_sizes, int n_in,
                              void* d_out, int out_size, void* d_ws, size_t ws_size,
                              hipStream_t stream) {
  const float* x = (const float*)d_in[0];
  const float* kin = (const float*)d_in[1];
  float* y = (float*)d_out;
  const int H = in_sizes[1] / 4096;    // 768
  const int BH = in_sizes[0] / 4096;   // 6144
  float2* kf = (float2*)d_ws;          // 768*2049*8B = 12.59 MB
  float2* tw = kf + (size_t)H * KF_LD; // 16 KB
  float2* utw = tw + 2048;             // 8.2 KB
  hipLaunchKernelGGL(init_tables, dim3(13), dim3(NT), 0, stream, tw, utw);
  hipLaunchKernelGGL(kfft_kernel, dim3(H), dim3(NT), 0, stream, kin, kf, tw, utw);
  hipLaunchKernelGGL(conv_kernel, dim3(BH), dim3(NT), 0, stream, x, kf, tw, utw, y, H);
}

// Round 6
// 76.555 us; speedup vs baseline: 1.1380x; 1.1186x over previous
//
#include <hip/hip_runtime.h>
#include <math.h>

// FFT circular conv: y[b,h,:] = irfft(rfft(x[b,h,:]) * rfft(k[h,:])), N=4096.
// M=2048 complex FFT via even/odd packing. Stockham radix 8,8,8,4 with
// ping-pong LDS (one barrier per stage), float2 interleaved (b64 access),
// on-the-fly sincos twiddles (no VMEM on the critical path), pointwise
// multiply fused into fwd final stage, global load/store fused into
// first/last stages.

#define NT 256
#define KF_LD 2049
#define C_SQRT1_2 0.70710678118654752f
#define TWO_PI_OVER_M 3.0679615757712823e-3f  // 2*pi/2048
#define TWO_PI_OVER_N 1.5339807878856412e-3f  // 2*pi/4096

typedef float f2v __attribute__((ext_vector_type(2)));  // native vec for NT store

__device__ __forceinline__ void nt_store2(float2 v, float2* p) {
  f2v w; w.x = v.x; w.y = v.y;
  __builtin_nontemporal_store(w, (f2v*)p);
}

// Element-index swizzle for float2 LDS: spreads stride-16/128/256/512
// patterns to ~2 lanes per 8B slot. Involution (bits 4-7 XOR into 0-3).
__device__ __forceinline__ int SWE(int e) { return e ^ ((e >> 4) & 15); }

template <int SIGN>
__device__ __forceinline__ void bf8(const float2 a[8], float2 b[8]) {
  float s0r = a[0].x + a[4].x, s0i = a[0].y + a[4].y;
  float s1r = a[0].x - a[4].x, s1i = a[0].y - a[4].y;
  float s2r = a[2].x + a[6].x, s2i = a[2].y + a[6].y;
  float s3r = a[2].x - a[6].x, s3i = a[2].y - a[6].y;
  float E0r = s0r + s2r, E0i = s0i + s2i;
  float E2r = s0r - s2r, E2i = s0i - s2i;
  float E1r, E1i, E3r, E3i;
  if (SIGN < 0) { E1r = s1r + s3i; E1i = s1i - s3r; E3r = s1r - s3i; E3i = s1i + s3r; }
  else          { E1r = s1r - s3i; E1i = s1i + s3r; E3r = s1r + s3i; E3i = s1i - s3r; }
  float u0r = a[1].x + a[5].x, u0i = a[1].y + a[5].y;
  float u1r = a[1].x - a[5].x, u1i = a[1].y - a[5].y;
  float u2r = a[3].x + a[7].x, u2i = a[3].y + a[7].y;
  float u3r = a[3].x - a[7].x, u3i = a[3].y - a[7].y;
  float O0r = u0r + u2r, O0i = u0i + u2i;
  float O2r = u0r - u2r, O2i = u0i - u2i;
  float O1r, O1i, O3r, O3i;
  if (SIGN < 0) { O1r = u1r + u3i; O1i = u1i - u3r; O3r = u1r - u3i; O3i = u1i + u3r; }
  else          { O1r = u1r - u3i; O1i = u1i + u3r; O3r = u1r + u3i; O3i = u1i - u3r; }
  float t1r, t1i, t2r, t2i, t3r, t3i;
  if (SIGN < 0) {
    t1r = C_SQRT1_2 * (O1r + O1i); t1i = C_SQRT1_2 * (O1i - O1r);
    t2r = O2i;  t2i = -O2r;
    t3r = C_SQRT1_2 * (O3i - O3r); t3i = -C_SQRT1_2 * (O3r + O3i);
  } else {
    t1r = C_SQRT1_2 * (O1r - O1i); t1i = C_SQRT1_2 * (O1i + O1r);
    t2r = -O2i; t2i = O2r;
    t3r = -C_SQRT1_2 * (O3r + O3i); t3i = C_SQRT1_2 * (O3r - O3i);
  }
  b[0] = make_float2(E0r + O0r, E0i + O0i);
  b[4] = make_float2(E0r - O0r, E0i - O0i);
  b[1] = make_float2(E1r + t1r, E1i + t1i);
  b[5] = make_float2(E1r - t1r, E1i - t1i);
  b[2] = make_float2(E2r + t2r, E2i + t2i);
  b[6] = make_float2(E2r - t2r, E2i - t2i);
  b[3] = make_float2(E3r + t3r, E3i + t3i);
  b[7] = make_float2(E3r - t3r, E3i - t3i);
}

// Twiddled scatter-write of b[0..7] to Y at base ob, stride S:
// Y[ob+S*m] = b[m] * w^m, w = e^{SIGN*i*theta1}. Pure-VALU twiddles.
template <int SIGN, int S>
__device__ __forceinline__ void tw_write(float2* Y, int ob, const float2 b[8],
                                         float theta1) {
  Y[SWE(ob)] = b[0];
  float sn, cs;
  __sincosf(theta1, &sn, &cs);
  const float w1r = cs, w1i = (SIGN > 0) ? sn : -sn;
  float cwr = w1r, cwi = w1i;
#pragma unroll
  for (int m = 1; m < 8; ++m) {
    Y[SWE(ob + S * m)] = make_float2(b[m].x * cwr - b[m].y * cwi,
                                     b[m].x * cwi + b[m].y * cwr);
    if (m < 7) {
      const float nr = cwr * w1r - cwi * w1i;
      const float ni = cwr * w1i + cwi * w1r;
      cwr = nr; cwi = ni;
    }
  }
}

// Out-of-place Stockham radix-8 stage: read X[t+256j], write Y (twiddled).
// No internal barrier — caller syncs after.
template <int SIGN, int S>
__device__ __forceinline__ void stage_r8(const float2* X, float2* Y,
                                         const int rd[8]) {
  const int t = (int)threadIdx.x;
  const int q = t & (S - 1);
  const int p = t / S;
  float2 a[8];
#pragma unroll
  for (int j = 0; j < 8; ++j) a[j] = X[rd[j]];
  float2 b[8];
  bf8<SIGN>(a, b);
  tw_write<SIGN, S>(Y, q + 8 * S * p, b, TWO_PI_OVER_M * (float)(S * p));
}

// Stage 1 (S=1) fused with the global load (src = packed complex row).
template <int SIGN>
__device__ __forceinline__ void stage1_global(const float2* __restrict__ src,
                                              float2* Y) {
  const int t = (int)threadIdx.x;
  float2 a[8];
#pragma unroll
  for (int j = 0; j < 8; ++j) a[j] = src[t + 256 * j];
  float2 b[8];
  bf8<SIGN>(a, b);
  tw_write<SIGN, 1>(Y, 8 * t, b, TWO_PI_OVER_M * (float)t);
}

// Forward radix-4 final-stage butterfly (twiddle-free), reads X.
__device__ __forceinline__ void bf4f(const float2* X, int b, float2 o[4]) {
  float2 a0 = X[SWE(b)], a1 = X[SWE(b + 512)];
  float2 a2 = X[SWE(b + 1024)], a3 = X[SWE(b + 1536)];
  float s0r = a0.x + a2.x, s0i = a0.y + a2.y;
  float s1r = a0.x - a2.x, s1i = a0.y - a2.y;
  float s2r = a1.x + a3.x, s2i = a1.y + a3.y;
  float s3r = a1.x - a3.x, s3i = a1.y - a3.y;
  o[0] = make_float2(s0r + s2r, s0i + s2i);
  o[1] = make_float2(s1r + s3i, s1i - s3r);
  o[2] = make_float2(s0r - s2r, s0i - s2i);
  o[3] = make_float2(s1r - s3i, s1i + s3r);
}

// rfft-unpack of conjugate pair (klo, 2048-klo), pointwise multiply by kf,
// repack to Z2 values for the inverse complex FFT. Twiddle via sincos.
__device__ __forceinline__ void pw_pair(int klo, float2 P, float2 Q,
                                        const float2* __restrict__ kfrow,
                                        float2& zlo, float2& zhi) {
  const float Er = 0.5f * (P.x + Q.x), Ei = 0.5f * (P.y - Q.y);
  const float Or = 0.5f * (P.y + Q.y), Oi = 0.5f * (Q.x - P.x);
  float sn, cs;
  __sincosf(TWO_PI_OVER_N * (float)klo, &sn, &cs);
  const float Xpr = Er + cs * Or + sn * Oi, Xpi = Ei + cs * Oi - sn * Or;
  const float Xqr = Er - cs * Or - sn * Oi, Xqi = -Ei + cs * Oi - sn * Or;
  const float2 Kp = kfrow[klo];
  const float2 Kq = kfrow[2048 - klo];
  const float Ypr = Xpr * Kp.x - Xpi * Kp.y, Ypi = Xpr * Kp.y + Xpi * Kp.x;
  const float Yqr = Xqr * Kq.x - Xqi * Kq.y, Yqi = Xqr * Kq.y + Xqi * Kq.x;
  const float Epr = 0.5f * (Ypr + Yqr), Epi = 0.5f * (Ypi - Yqi);
  const float Dr = 0.5f * (Ypr - Yqr), Di = 0.5f * (Ypi + Yqi);
  zlo = make_float2(Epr - cs * Di - sn * Dr, Epi + cs * Dr - sn * Di);
  zhi = make_float2(Epr + cs * Di + sn * Dr, -Epi + cs * Dr - sn * Di);
}

// Forward final radix-4 stage fused with unpack * kf * repack, out-of-place
// (read X, write Y). Thread t does butterflies t and 512-t (t=0: 0 and 256):
// their 8 outputs form exactly the conjugate pairs (kk, 2048-kk).
__device__ __forceinline__ void fwd4_pw(const float2* X, float2* Y,
                                        const float2* __restrict__ kfrow) {
  const int t = (int)threadIdx.x;
  const int b1 = (t == 0) ? 256 : 512 - t;
  float2 A[4], B[4];
  bf4f(X, t, A);
  bf4f(X, b1, B);
  int k0, k1, k2, k3;
  float2 zl0, zh0, zl1, zh1, zl2, zh2, zl3, zh3, zl4;
  zl4 = make_float2(0.f, 0.f);
  if (t == 0) {
    float2 zh4;
    k0 = 0;   pw_pair(0, A[0], A[0], kfrow, zl0, zh0);
    k1 = 512; pw_pair(512, A[1], A[3], kfrow, zl1, zh1);
    k2 = 256; pw_pair(256, B[0], B[3], kfrow, zl2, zh2);
    k3 = 768; pw_pair(768, B[1], B[2], kfrow, zl3, zh3);
    pw_pair(1024, A[2], A[2], kfrow, zl4, zh4);
  } else {
    k0 = t;        pw_pair(k0, A[0], B[3], kfrow, zl0, zh0);
    k1 = t + 512;  pw_pair(k1, A[1], B[2], kfrow, zl1, zh1);
    k2 = 1024 - t; pw_pair(k2, B[1], A[2], kfrow, zl2, zh2);
    k3 = 512 - t;  pw_pair(k3, B[0], A[3], kfrow, zl3, zh3);
  }
  Y[SWE(k0)] = zl0; Y[SWE((2048 - k0) & 2047)] = zh0;
  Y[SWE(k1)] = zl1; Y[SWE(2048 - k1)] = zh1;
  Y[SWE(k2)] = zl2; Y[SWE(2048 - k2)] = zh2;
  Y[SWE(k3)] = zl3; Y[SWE(2048 - k3)] = zh3;
  if (t == 0) Y[SWE(1024)] = zl4;
}

// Inverse final radix-4 stage (twiddle-free) fused with the global store.
__device__ __forceinline__ void inv4_store(const float2* X, float2* __restrict__ dst) {
  const int t = (int)threadIdx.x;
#pragma unroll
  for (int c = 0; c < 2; ++c) {
    const int b = t + 256 * c;
    float2 a0 = X[SWE(b)], a1 = X[SWE(b + 512)];
    float2 a2 = X[SWE(b + 1024)], a3 = X[SWE(b + 1536)];
    float s0r = a0.x + a2.x, s0i = a0.y + a2.y;
    float s1r = a0.x - a2.x, s1i = a0.y - a2.y;
    float s2r = a1.x + a3.x, s2i = a1.y + a3.y;
    float s3r = a1.x - a3.x, s3i = a1.y - a3.y;
    nt_store2(make_float2(s0r + s2r, s0i + s2i), &dst[b]);
    nt_store2(make_float2(s1r - s3i, s1i + s3r), &dst[b + 512]);
    nt_store2(make_float2(s0r - s2r, s0i - s2i), &dst[b + 1024]);
    nt_store2(make_float2(s1r + s3i, s1i - s3r), &dst[b + 1536]);
  }
}

// Forward radix-4 final stage, plain, out-of-place (kfft path).
__device__ __forceinline__ void stage_r4_fwd(const float2* X, float2* Y) {
  const int t = (int)threadIdx.x;
  float2 O0[4], O1[4];
  bf4f(X, t, O0);
  bf4f(X, t + 256, O1);
#pragma unroll
  for (int m = 0; m < 4; ++m) {
    Y[SWE(t + 512 * m)] = O0[m];
    Y[SWE(t + 256 + 512 * m)] = O1[m];
  }
}

__device__ __forceinline__ void unpackX(float2 P, float2 Q, int kk,
                                        float2& Xp, float2& Xq) {
  const float Er = 0.5f * (P.x + Q.x), Ei = 0.5f * (P.y - Q.y);
  const float Or = 0.5f * (P.y + Q.y), Oi = 0.5f * (Q.x - P.x);
  float sn, cs;
  __sincosf(TWO_PI_OVER_N * (float)kk, &sn, &cs);
  Xp = make_float2(Er + cs * Or + sn * Oi, Ei + cs * Oi - sn * Or);
  Xq = make_float2(Er - cs * Or - sn * Oi, -Ei + cs * Oi - sn * Or);
}

__global__ __launch_bounds__(NT) void kfft_kernel(const float* __restrict__ kin,
                                                  float2* __restrict__ kf) {
  __shared__ float2 ZA[2048];
  __shared__ float2 ZB[2048];
  const int t = (int)threadIdx.x;
  const int h = (int)blockIdx.x;
  const float2* src = (const float2*)(kin + (size_t)h * 4096);
  int rd[8];
#pragma unroll
  for (int j = 0; j < 8; ++j) rd[j] = SWE(t + 256 * j);
  stage1_global<-1>(src, ZA);
  __syncthreads();
  stage_r8<-1, 8>(ZA, ZB, rd);
  __syncthreads();
  stage_r8<-1, 64>(ZB, ZA, rd);
  __syncthreads();
  stage_r4_fwd(ZA, ZB);
  __syncthreads();
  const float sc = 1.0f / 2048.0f;  // folded inverse-FFT normalization
  float2* kfrow = kf + (size_t)h * KF_LD;
#pragma unroll
  for (int u = 0; u < 4; ++u) {
    const int kk = t + 256 * u;  // 0..1023
    const float2 P = ZB[SWE(kk)];
    const float2 Q = ZB[SWE((2048 - kk) & 2047)];
    float2 Xp, Xq;
    unpackX(P, Q, kk, Xp, Xq);
    kfrow[kk] = make_float2(Xp.x * sc, Xp.y * sc);
    kfrow[2048 - kk] = make_float2(Xq.x * sc, Xq.y * sc);
  }
  if (t == 0) {
    const float2 P = ZB[SWE(1024)];
    float2 Xp, Xq;
    unpackX(P, P, 1024, Xp, Xq);
    kfrow[1024] = make_float2(Xp.x * sc, Xp.y * sc);
  }
}

__global__ __launch_bounds__(NT) void conv_kernel(const float* __restrict__ x,
                                                  const float2* __restrict__ kf,
                                                  float* __restrict__ y, int H) {
  __shared__ float2 ZA[2048];
  __shared__ float2 ZB[2048];
  const int t = (int)threadIdx.x;
  const int bi = (int)blockIdx.x;
  const int b = bi & 7;   // batch (8 consecutive blocks share one kf row)
  const int h = bi >> 3;
  const int row = b * H + h;
  const float2* src = (const float2*)(x + (size_t)row * 4096);
  float2* dst = (float2*)(y + (size_t)row * 4096);
  const float2* kfrow = kf + (size_t)h * KF_LD;
  int rd[8];
#pragma unroll
  for (int j = 0; j < 8; ++j) rd[j] = SWE(t + 256 * j);
  stage1_global<-1>(src, ZA);      // fwd S=1 (r8), fused global load
  __syncthreads();
  stage_r8<-1, 8>(ZA, ZB, rd);     // fwd S=8
  __syncthreads();
  stage_r8<-1, 64>(ZB, ZA, rd);    // fwd S=64
  __syncthreads();
  fwd4_pw(ZA, ZB, kfrow);          // fwd S=512 (r4) + pointwise, fused
  __syncthreads();
  stage_r8<1, 1>(ZB, ZA, rd);      // inv S=1
  __syncthreads();
  stage_r8<1, 8>(ZA, ZB, rd);      // inv S=8
  __syncthreads();
  stage_r8<1, 64>(ZB, ZA, rd);     // inv S=64
  __syncthreads();
  inv4_store(ZA, dst);             // inv S=512 (r4), fused global store
}

extern "C" void kernel_launch(void* const* d_in, const int* in_sizes, int n_in,
                              void* d_out, int out_size, void* d_ws, size_t ws_size,
                              hipStream_t stream) {
  const float* x = (const float*)d_in[0];
  const float* kin = (const float*)d_in[1];
  float* y = (float*)d_out;
  const int H = in_sizes[1] / 4096;    // 768
  const int BH = in_sizes[0] / 4096;   // 6144
  float2* kf = (float2*)d_ws;          // 768*2049*8B = 12.59 MB
  hipLaunchKernelGGL(kfft_kernel, dim3(H), dim3(NT), 0, stream, kin, kf);
  hipLaunchKernelGGL(conv_kernel, dim3(BH), dim3(NT), 0, stream, x, kf, y, H);
}

// Round 7
// 63.833 us; speedup vs baseline: 1.3648x; 1.1993x over previous
//
#include <hip/hip_runtime.h>
#include <math.h>

// FFT circular conv: y[b,h,:] = irfft(rfft(x[b,h,:]) * rfft(k[h,:])), N=4096.
// M=2048 complex FFT via even/odd packing. Stockham radix 8,8,8,4.
// Separate re/im b32 LDS arrays (2 lanes/bank = free), SW word swizzle,
// ping-pong (one barrier per stage), on-the-fly sincos twiddle chains,
// pointwise multiply fused into fwd final stage, global load/store fused
// into first/last stages. Plain stores, plain block mapping (round-2 proven).

#define NT 256
#define KF_LD 2049
#define C_SQRT1_2 0.70710678118654752f
#define TWO_PI_OVER_M 3.0679615757712823e-3f  // 2*pi/2048
#define TWO_PI_OVER_N 1.5339807878856412e-3f  // 2*pi/4096

// Word-level LDS swizzle: spreads stride-8/64/512 scatter patterns to
// <=2 lanes/bank (free); bijective within 2048.
#define SW(a) ((a) ^ (((a) >> 5) & 31))

template <int SIGN>
__device__ __forceinline__ void bf8(const float ar[8], const float ai[8],
                                    float br[8], float bi[8]) {
  float s0r = ar[0] + ar[4], s0i = ai[0] + ai[4];
  float s1r = ar[0] - ar[4], s1i = ai[0] - ai[4];
  float s2r = ar[2] + ar[6], s2i = ai[2] + ai[6];
  float s3r = ar[2] - ar[6], s3i = ai[2] - ai[6];
  float E0r = s0r + s2r, E0i = s0i + s2i;
  float E2r = s0r - s2r, E2i = s0i - s2i;
  float E1r, E1i, E3r, E3i;
  if (SIGN < 0) { E1r = s1r + s3i; E1i = s1i - s3r; E3r = s1r - s3i; E3i = s1i + s3r; }
  else          { E1r = s1r - s3i; E1i = s1i + s3r; E3r = s1r + s3i; E3i = s1i - s3r; }
  float u0r = ar[1] + ar[5], u0i = ai[1] + ai[5];
  float u1r = ar[1] - ar[5], u1i = ai[1] - ai[5];
  float u2r = ar[3] + ar[7], u2i = ai[3] + ai[7];
  float u3r = ar[3] - ar[7], u3i = ai[3] - ai[7];
  float O0r = u0r + u2r, O0i = u0i + u2i;
  float O2r = u0r - u2r, O2i = u0i - u2i;
  float O1r, O1i, O3r, O3i;
  if (SIGN < 0) { O1r = u1r + u3i; O1i = u1i - u3r; O3r = u1r - u3i; O3i = u1i + u3r; }
  else          { O1r = u1r - u3i; O1i = u1i + u3r; O3r = u1r + u3i; O3i = u1i - u3r; }
  float t1r, t1i, t2r, t2i, t3r, t3i;
  if (SIGN < 0) {
    t1r = C_SQRT1_2 * (O1r + O1i); t1i = C_SQRT1_2 * (O1i - O1r);
    t2r = O2i;  t2i = -O2r;
    t3r = C_SQRT1_2 * (O3i - O3r); t3i = -C_SQRT1_2 * (O3r + O3i);
  } else {
    t1r = C_SQRT1_2 * (O1r - O1i); t1i = C_SQRT1_2 * (O1i + O1r);
    t2r = -O2i; t2i = O2r;
    t3r = -C_SQRT1_2 * (O3r + O3i); t3i = C_SQRT1_2 * (O3r - O3i);
  }
  br[0] = E0r + O0r; bi[0] = E0i + O0i;
  br[4] = E0r - O0r; bi[4] = E0i - O0i;
  br[1] = E1r + t1r; bi[1] = E1i + t1i;
  br[5] = E1r - t1r; bi[5] = E1i - t1i;
  br[2] = E2r + t2r; bi[2] = E2i + t2i;
  br[6] = E2r - t2r; bi[6] = E2i - t2i;
  br[3] = E3r + t3r; bi[3] = E3i + t3i;
  br[7] = E3r - t3r; bi[7] = E3i - t3i;
}

// Twiddled scatter-write: Y[ob+S*m] = b[m] * w^m, w = e^{SIGN*i*theta1}.
template <int SIGN, int S>
__device__ __forceinline__ void tw_write(float* Yr, float* Yi, int ob,
                                         const float br[8], const float bi[8],
                                         float theta1) {
  { const int i0 = SW(ob); Yr[i0] = br[0]; Yi[i0] = bi[0]; }
  float sn, cs;
  __sincosf(theta1, &sn, &cs);
  const float w1r = cs, w1i = (SIGN > 0) ? sn : -sn;
  float cwr = w1r, cwi = w1i;
#pragma unroll
  for (int m = 1; m < 8; ++m) {
    const int idx = SW(ob + S * m);
    Yr[idx] = br[m] * cwr - bi[m] * cwi;
    Yi[idx] = br[m] * cwi + bi[m] * cwr;
    if (m < 7) {
      const float nr = cwr * w1r - cwi * w1i;
      const float ni = cwr * w1i + cwi * w1r;
      cwr = nr; cwi = ni;
    }
  }
}

// Out-of-place Stockham radix-8 stage. No internal barrier.
template <int SIGN, int S>
__device__ __forceinline__ void stage_r8(const float* Xr, const float* Xi,
                                         float* Yr, float* Yi) {
  const int t = (int)threadIdx.x;
  const int q = t & (S - 1);
  const int p = t / S;
  float ar[8], ai[8];
#pragma unroll
  for (int j = 0; j < 8; ++j) {
    const int idx = SW(t + 256 * j);
    ar[j] = Xr[idx];
    ai[j] = Xi[idx];
  }
  float br[8], bi[8];
  bf8<SIGN>(ar, ai, br, bi);
  tw_write<SIGN, S>(Yr, Yi, q + 8 * S * p, br, bi,
                    TWO_PI_OVER_M * (float)(S * p));
}

// Stage 1 (S=1) fused with the global load (src = packed complex row).
template <int SIGN>
__device__ __forceinline__ void stage1_global(const float2* __restrict__ src,
                                              float* Yr, float* Yi) {
  const int t = (int)threadIdx.x;
  float ar[8], ai[8];
#pragma unroll
  for (int j = 0; j < 8; ++j) {
    const float2 v = src[t + 256 * j];
    ar[j] = v.x; ai[j] = v.y;
  }
  float br[8], bi[8];
  bf8<SIGN>(ar, ai, br, bi);
  tw_write<SIGN, 1>(Yr, Yi, 8 * t, br, bi, TWO_PI_OVER_M * (float)t);
}

// Forward radix-4 final-stage butterfly (twiddle-free), reads X at base b.
__device__ __forceinline__ void bf4f(const float* Xr, const float* Xi, int b,
                                     float orr[4], float oi[4]) {
  const int i0 = SW(b), i1 = SW(b + 512), i2 = SW(b + 1024), i3 = SW(b + 1536);
  float a0r = Xr[i0], a0i = Xi[i0];
  float a1r = Xr[i1], a1i = Xi[i1];
  float a2r = Xr[i2], a2i = Xi[i2];
  float a3r = Xr[i3], a3i = Xi[i3];
  float s0r = a0r + a2r, s0i = a0i + a2i;
  float s1r = a0r - a2r, s1i = a0i - a2i;
  float s2r = a1r + a3r, s2i = a1i + a3i;
  float s3r = a1r - a3r, s3i = a1i - a3i;
  orr[0] = s0r + s2r; oi[0] = s0i + s2i;
  orr[1] = s1r + s3i; oi[1] = s1i - s3r;
  orr[2] = s0r - s2r; oi[2] = s0i - s2i;
  orr[3] = s1r - s3i; oi[3] = s1i + s3r;
}

// rfft-unpack of conjugate pair (klo, 2048-klo), multiply by kf, repack.
__device__ __forceinline__ void pw_pair(int klo, float Pr, float Pi, float Qr,
                                        float Qi, const float2* __restrict__ kfrow,
                                        float2& zlo, float2& zhi) {
  const float Er = 0.5f * (Pr + Qr), Ei = 0.5f * (Pi - Qi);
  const float Or = 0.5f * (Pi + Qi), Oi = 0.5f * (Qr - Pr);
  float sn, cs;
  __sincosf(TWO_PI_OVER_N * (float)klo, &sn, &cs);
  const float Xpr = Er + cs * Or + sn * Oi, Xpi = Ei + cs * Oi - sn * Or;
  const float Xqr = Er - cs * Or - sn * Oi, Xqi = -Ei + cs * Oi - sn * Or;
  const float2 Kp = kfrow[klo];
  const float2 Kq = kfrow[2048 - klo];
  const float Ypr = Xpr * Kp.x - Xpi * Kp.y, Ypi = Xpr * Kp.y + Xpi * Kp.x;
  const float Yqr = Xqr * Kq.x - Xqi * Kq.y, Yqi = Xqr * Kq.y + Xqi * Kq.x;
  const float Epr = 0.5f * (Ypr + Yqr), Epi = 0.5f * (Ypi - Yqi);
  const float Dr = 0.5f * (Ypr - Yqr), Di = 0.5f * (Ypi + Yqi);
  zlo = make_float2(Epr - cs * Di - sn * Dr, Epi + cs * Dr - sn * Di);
  zhi = make_float2(Epr + cs * Di + sn * Dr, -Epi + cs * Dr - sn * Di);
}

// Forward final radix-4 stage fused with unpack * kf * repack, out-of-place.
// Thread t does butterflies t and 512-t (t=0: 0 and 256): their 8 outputs
// form exactly the conjugate pairs (kk, 2048-kk).
__device__ __forceinline__ void fwd4_pw(const float* Xr, const float* Xi,
                                        float* Yr, float* Yi,
                                        const float2* __restrict__ kfrow) {
  const int t = (int)threadIdx.x;
  const int b1 = (t == 0) ? 256 : 512 - t;
  float Ar[4], Ai[4], Br[4], Bi[4];
  bf4f(Xr, Xi, t, Ar, Ai);
  bf4f(Xr, Xi, b1, Br, Bi);
  int k0, k1, k2, k3;
  float2 zl0, zh0, zl1, zh1, zl2, zh2, zl3, zh3, zl4;
  zl4 = make_float2(0.f, 0.f);
  if (t == 0) {
    float2 zh4;
    k0 = 0;   pw_pair(0,   Ar[0], Ai[0], Ar[0], Ai[0], kfrow, zl0, zh0);
    k1 = 512; pw_pair(512, Ar[1], Ai[1], Ar[3], Ai[3], kfrow, zl1, zh1);
    k2 = 256; pw_pair(256, Br[0], Bi[0], Br[3], Bi[3], kfrow, zl2, zh2);
    k3 = 768; pw_pair(768, Br[1], Bi[1], Br[2], Bi[2], kfrow, zl3, zh3);
    pw_pair(1024, Ar[2], Ai[2], Ar[2], Ai[2], kfrow, zl4, zh4);
  } else {
    k0 = t;        pw_pair(k0, Ar[0], Ai[0], Br[3], Bi[3], kfrow, zl0, zh0);
    k1 = t + 512;  pw_pair(k1, Ar[1], Ai[1], Br[2], Bi[2], kfrow, zl1, zh1);
    k2 = 1024 - t; pw_pair(k2, Br[1], Bi[1], Ar[2], Ai[2], kfrow, zl2, zh2);
    k3 = 512 - t;  pw_pair(k3, Br[0], Bi[0], Ar[3], Ai[3], kfrow, zl3, zh3);
  }
  {
    int i;
    i = SW(k0);                 Yr[i] = zl0.x; Yi[i] = zl0.y;
    i = SW((2048 - k0) & 2047); Yr[i] = zh0.x; Yi[i] = zh0.y;
    i = SW(k1);                 Yr[i] = zl1.x; Yi[i] = zl1.y;
    i = SW(2048 - k1);          Yr[i] = zh1.x; Yi[i] = zh1.y;
    i = SW(k2);                 Yr[i] = zl2.x; Yi[i] = zl2.y;
    i = SW(2048 - k2);          Yr[i] = zh2.x; Yi[i] = zh2.y;
    i = SW(k3);                 Yr[i] = zl3.x; Yi[i] = zl3.y;
    i = SW(2048 - k3);          Yr[i] = zh3.x; Yi[i] = zh3.y;
    if (t == 0) { i = SW(1024); Yr[i] = zl4.x; Yi[i] = zl4.y; }
  }
}

// Inverse final radix-4 stage (twiddle-free) fused with the global store.
__device__ __forceinline__ void inv4_store(const float* Xr, const float* Xi,
                                           float2* __restrict__ dst) {
  const int t = (int)threadIdx.x;
#pragma unroll
  for (int c = 0; c < 2; ++c) {
    const int b = t + 256 * c;
    const int i0 = SW(b), i1 = SW(b + 512), i2 = SW(b + 1024), i3 = SW(b + 1536);
    float a0r = Xr[i0], a0i = Xi[i0];
    float a1r = Xr[i1], a1i = Xi[i1];
    float a2r = Xr[i2], a2i = Xi[i2];
    float a3r = Xr[i3], a3i = Xi[i3];
    float s0r = a0r + a2r, s0i = a0i + a2i;
    float s1r = a0r - a2r, s1i = a0i - a2i;
    float s2r = a1r + a3r, s2i = a1i + a3i;
    float s3r = a1r - a3r, s3i = a1i - a3i;
    dst[b]        = make_float2(s0r + s2r, s0i + s2i);
    dst[b + 512]  = make_float2(s1r - s3i, s1i + s3r);
    dst[b + 1024] = make_float2(s0r - s2r, s0i - s2i);
    dst[b + 1536] = make_float2(s1r + s3i, s1i - s3r);
  }
}

// Forward radix-4 final stage, plain, out-of-place (kfft path).
__device__ __forceinline__ void stage_r4_fwd(const float* Xr, const float* Xi,
                                             float* Yr, float* Yi) {
  const int t = (int)threadIdx.x;
  float O0r[4], O0i[4], O1r[4], O1i[4];
  bf4f(Xr, Xi, t, O0r, O0i);
  bf4f(Xr, Xi, t + 256, O1r, O1i);
#pragma unroll
  for (int m = 0; m < 4; ++m) {
    int i;
    i = SW(t + 512 * m);       Yr[i] = O0r[m]; Yi[i] = O0i[m];
    i = SW(t + 256 + 512 * m); Yr[i] = O1r[m]; Yi[i] = O1i[m];
  }
}

__device__ __forceinline__ void unpackX(float Pr, float Pi, float Qr, float Qi,
                                        int kk, float2& Xp, float2& Xq) {
  const float Er = 0.5f * (Pr + Qr), Ei = 0.5f * (Pi - Qi);
  const float Or = 0.5f * (Pi + Qi), Oi = 0.5f * (Qr - Pr);
  float sn, cs;
  __sincosf(TWO_PI_OVER_N * (float)kk, &sn, &cs);
  Xp = make_float2(Er + cs * Or + sn * Oi, Ei + cs * Oi - sn * Or);
  Xq = make_float2(Er - cs * Or - sn * Oi, -Ei + cs * Oi - sn * Or);
}

__global__ __launch_bounds__(NT) void kfft_kernel(const float* __restrict__ kin,
                                                  float2* __restrict__ kf) {
  __shared__ float Ar_[2048], Ai_[2048], Br_[2048], Bi_[2048];
  const int t = (int)threadIdx.x;
  const int h = (int)blockIdx.x;
  const float2* src = (const float2*)(kin + (size_t)h * 4096);
  stage1_global<-1>(src, Ar_, Ai_);
  __syncthreads();
  stage_r8<-1, 8>(Ar_, Ai_, Br_, Bi_);
  __syncthreads();
  stage_r8<-1, 64>(Br_, Bi_, Ar_, Ai_);
  __syncthreads();
  stage_r4_fwd(Ar_, Ai_, Br_, Bi_);
  __syncthreads();
  const float sc = 1.0f / 2048.0f;  // folded inverse-FFT normalization
  float2* kfrow = kf + (size_t)h * KF_LD;
#pragma unroll
  for (int u = 0; u < 4; ++u) {
    const int kk = t + 256 * u;  // 0..1023
    const int ip = SW(kk), iq = SW((2048 - kk) & 2047);
    float2 Xp, Xq;
    unpackX(Br_[ip], Bi_[ip], Br_[iq], Bi_[iq], kk, Xp, Xq);
    kfrow[kk] = make_float2(Xp.x * sc, Xp.y * sc);
    kfrow[2048 - kk] = make_float2(Xq.x * sc, Xq.y * sc);
  }
  if (t == 0) {
    const int ip = SW(1024);
    float2 Xp, Xq;
    unpackX(Br_[ip], Bi_[ip], Br_[ip], Bi_[ip], 1024, Xp, Xq);
    kfrow[1024] = make_float2(Xp.x * sc, Xp.y * sc);
  }
}

__global__ __launch_bounds__(NT) void conv_kernel(const float* __restrict__ x,
                                                  const float2* __restrict__ kf,
                                                  float* __restrict__ y, int H) {
  __shared__ float Ar_[2048], Ai_[2048], Br_[2048], Bi_[2048];
  const int row = (int)blockIdx.x;
  const int h = row % H;
  const float2* src = (const float2*)(x + (size_t)row * 4096);
  float2* dst = (float2*)(y + (size_t)row * 4096);
  const float2* kfrow = kf + (size_t)h * KF_LD;
  stage1_global<-1>(src, Ar_, Ai_);      // fwd S=1 (r8), fused global load
  __syncthreads();
  stage_r8<-1, 8>(Ar_, Ai_, Br_, Bi_);   // fwd S=8
  __syncthreads();
  stage_r8<-1, 64>(Br_, Bi_, Ar_, Ai_);  // fwd S=64
  __syncthreads();
  fwd4_pw(Ar_, Ai_, Br_, Bi_, kfrow);    // fwd S=512 (r4) + pointwise, fused
  __syncthreads();
  stage_r8<1, 1>(Br_, Bi_, Ar_, Ai_);    // inv S=1
  __syncthreads();
  stage_r8<1, 8>(Ar_, Ai_, Br_, Bi_);    // inv S=8
  __syncthreads();
  stage_r8<1, 64>(Br_, Bi_, Ar_, Ai_);   // inv S=64
  __syncthreads();
  inv4_store(Ar_, Ai_, dst);             // inv S=512 (r4), fused global store
}

extern "C" void kernel_launch(void* const* d_in, const int* in_sizes, int n_in,
                              void* d_out, int out_size, void* d_ws, size_t ws_size,
                              hipStream_t stream) {
  const float* x = (const float*)d_in[0];
  const float* kin = (const float*)d_in[1];
  float* y = (float*)d_out;
  const int H = in_sizes[1] / 4096;    // 768
  const int BH = in_sizes[0] / 4096;   // 6144
  float2* kf = (float2*)d_ws;          // 768*2049*8B = 12.59 MB
  hipLaunchKernelGGL(kfft_kernel, dim3(H), dim3(NT), 0, stream, kin, kf);
  hipLaunchKernelGGL(conv_kernel, dim3(BH), dim3(NT), 0, stream, x, kf, y, H);
}